// Round 8
// baseline (229.060 us; speedup 1.0000x reference)
//
#include <hip/hip_runtime.h>
#include <hip/hip_bf16.h>

typedef __bf16 bf16_t;
typedef __bf16 bf16x8 __attribute__((ext_vector_type(8)));
typedef float  f32x4  __attribute__((ext_vector_type(4)));

#define DK 1024   // d_in  (K)
#define DN 1024   // d_out (N)
#define RNK 32
#define BM 128
#define BN 256
#define BK 32
#define NKT 32

// ---- Pass 1: W_eff = W + C @ V_r^T, bf16, PRE-SWIZZLED ---------------------
// Chunks [bn(4)][kt(32)] of 16KB = exact LDS image of a 256row x 32k tile.
// Element (rloc, kloc): byte = rloc*64 + ((seg ^ ((rloc>>1)&3))<<4) + (kloc&7)*2,
// seg = kloc>>3. Conflict-free for ds_read_b128 (verified pattern from R7).
__global__ void weff_kernel(const float* __restrict__ W,
                            const float* __restrict__ Vr,
                            const float* __restrict__ C,
                            bf16_t* __restrict__ WeffSw)
{
    const int o  = blockIdx.x;       // 0..1023 (d_out row)
    const int g  = threadIdx.x;      // 0..127  (8-wide d_in group)
    const int d0 = g * 8;

    f32x4 cv[8];
#pragma unroll
    for (int q = 0; q < 8; ++q) cv[q] = *(const f32x4*)(C + o * RNK + q * 4);

    const f32x4* wrow = (const f32x4*)(W + (size_t)o * DK + d0);
    f32x4 w0 = wrow[0], w1 = wrow[1];
    float acc[8];
#pragma unroll
    for (int e = 0; e < 4; ++e) { acc[e] = w0[e]; acc[4 + e] = w1[e]; }

#pragma unroll
    for (int e = 0; e < 8; ++e) {
        const f32x4* vre = (const f32x4*)(Vr + (size_t)(d0 + e) * RNK);
        float s = 0.f;
#pragma unroll
        for (int q = 0; q < 8; ++q) {
            f32x4 v = vre[q];
            s += cv[q][0] * v[0] + cv[q][1] * v[1] + cv[q][2] * v[2] + cv[q][3] * v[3];
        }
        acc[e] += s;
    }

    bf16x8 out;
#pragma unroll
    for (int e = 0; e < 8; ++e) out[e] = (bf16_t)acc[e];

    const int bn = o >> 8, rloc = o & 255;
    const int kt = d0 >> 5, seg = (d0 >> 3) & 3;
    const int sw = seg ^ ((rloc >> 1) & 3);
    const size_t byte = (size_t)(bn * 32 + kt) * 16384 + rloc * 64 + (sw << 4);
    *(bf16x8*)((char*)WeffSw + byte) = out;
}

// ---- Pass 2: 128x256 tile, BK=32, 8 waves (2x4) of 64x64 -------------------
// acc=64 AGPR -> total regs capped at 128 (launch_bounds 4 waves/EU):
// 4 waves/SIMD, 2 independent blocks/CU -> MFMA/LDS overlap via TLP.
__global__ __launch_bounds__(512, 4) void corrlin_gemm_kernel(
    const float* __restrict__ X, const bf16_t* __restrict__ WeffSw,
    const float* __restrict__ bias, float* __restrict__ Out)
{
    __shared__ __align__(16) char smem[49152];
    char* Ab0 = smem;                 // 8KB each (128 rows x 32 k bf16)
    char* Ab1 = smem + 8192;
    char* Bb0 = smem + 16384;         // 16KB each (256 rows x 32 k bf16)
    char* Bb1 = smem + 32768;

    const int tid = threadIdx.x;
    const int nwg = gridDim.x;        // 2048
    const int b0  = blockIdx.x;
    const int L   = (b0 & 7) * (nwg >> 3) + (b0 >> 3);   // XCD-bijective
    const int bm  = L >> 2;           // 512 m-tiles
    const int bn  = L & 3;            // 4 n-tiles
    const int m0  = bm * BM;

    const int lane = tid & 63;
    const int wid  = tid >> 6;        // 0..7
    const int wm   = wid >> 2;        // 0..1 (64-row half)
    const int wn   = wid & 3;         // 0..3 (64-col quarter)
    const int arow = tid >> 2;        // 0..127
    const int aseg = tid & 3;         // 0..3 (16B chunk in 64B row)

    f32x4 acc[4][4] = {};             // 64 AGPR
    f32x4 set0[2], set1[2];           // depth-2 A prefetch (named sets)

    auto issueA = [&](int kt, f32x4* s) {
        const float* p = X + (size_t)(m0 + arow) * DK + kt * BK + aseg * 8;
        s[0] = *(const f32x4*)p;
        s[1] = *(const f32x4*)(p + 4);
    };
    auto storeA = [&](const f32x4* s, char* Ab) {
        const int sw = aseg ^ ((arow >> 1) & 3);
        bf16x8 v;
#pragma unroll
        for (int j = 0; j < 4; ++j) { v[j] = (bf16_t)s[0][j]; v[4 + j] = (bf16_t)s[1][j]; }
        *(bf16x8*)(Ab + arow * 64 + (sw << 4)) = v;
    };
    auto issueB = [&](int kt, char* Bb) {
        const char* g = (const char*)WeffSw + (size_t)(bn * 32 + kt) * 16384;
#pragma unroll
        for (int c = 0; c < 2; ++c) {
            const int lin = wid * 2048 + c * 1024;       // wave-uniform dest
            __builtin_amdgcn_global_load_lds(
                (const __attribute__((address_space(1))) void*)(g + lin + lane * 16),
                (__attribute__((address_space(3))) void*)(Bb + lin),
                16, 0, 0);
        }
    };
    auto readB = [&](const char* Bc, bf16x8* bfr) {
        const int kb = lane >> 4;
#pragma unroll
        for (int nf = 0; nf < 4; ++nf) {
            const int row = wn * 64 + nf * 16 + (lane & 15);
            bfr[nf] = *(const bf16x8*)(Bc + row * 64 + ((kb ^ ((row >> 1) & 3)) << 4));
        }
    };
    auto compute = [&](const char* Ac, const bf16x8* bfr) {
        bf16x8 af[4];
        const int kb = lane >> 4;
#pragma unroll
        for (int i = 0; i < 4; ++i) {
            const int row = wm * 64 + i * 16 + (lane & 15);
            af[i] = *(const bf16x8*)(Ac + row * 64 + ((kb ^ ((row >> 1) & 3)) << 4));
        }
        __builtin_amdgcn_s_setprio(1);
#pragma unroll
        for (int mf = 0; mf < 4; ++mf)
#pragma unroll
            for (int nf = 0; nf < 4; ++nf)
                acc[mf][nf] = __builtin_amdgcn_mfma_f32_16x16x32_bf16(
                    af[mf], bfr[nf], acc[mf][nf], 0, 0, 0);
        __builtin_amdgcn_s_setprio(0);
    };

    auto iter = [&](int t, const char* Ac, const char* Bc, char* An, char* Bn,
                    f32x4* aStore /*holds A(t+1)*/, f32x4* aFill /*gets A(t+2)*/) {
        if (t + 1 < NKT) issueB(t + 1, Bn);   // oldest VMEM this iter
        bf16x8 bfr[4];
        readB(Bc, bfr);
        if (t + 1 < NKT) storeA(aStore, An);  // auto-waits A(t+1) regs only
        if (t + 2 < NKT) issueA(t + 2, aFill);
        compute(Ac, bfr);
        if (t + 2 < NKT) {
            asm volatile("s_waitcnt vmcnt(2) lgkmcnt(0)" ::: "memory");  // drain B(t+1), keep A(t+2)
            __builtin_amdgcn_s_barrier();
        } else if (t + 1 < NKT) {
            asm volatile("s_waitcnt vmcnt(0) lgkmcnt(0)" ::: "memory");
            __builtin_amdgcn_s_barrier();
        }
    };

    // ---- prologue: A(0)->LDS, A(1) in regs, B(0) staged ----
    issueA(0, set0);
    issueB(0, Bb0);
    storeA(set0, Ab0);               // auto-waits A(0) (vmcnt(2): B(0) stays)
    issueA(1, set1);
    asm volatile("s_waitcnt vmcnt(2) lgkmcnt(0)" ::: "memory");  // B(0) done, A(1) flying
    __builtin_amdgcn_s_barrier();

    for (int t = 0; t < NKT; t += 2) {
        iter(t,     Ab0, Bb0, Ab1, Bb1, set1, set0);
        iter(t + 1, Ab1, Bb1, Ab0, Bb0, set0, set1);
    }
    __syncthreads();                 // LDS free for epilogue reuse

    // ---- epilogue: per-wave LDS transpose -> full-line f32x4 stores --------
    float* tb = (float*)smem + wid * 1280;   // 16 x 80 f32 per wave (40KB)
    const int mbase = m0 + wm * 64;
    const int nbase = bn * BN + wn * 64;
    float bv[4];
#pragma unroll
    for (int nf = 0; nf < 4; ++nf) bv[nf] = bias[nbase + nf * 16 + (lane & 15)];

#pragma unroll
    for (int mf = 0; mf < 4; ++mf) {
#pragma unroll
        for (int nf = 0; nf < 4; ++nf)
#pragma unroll
            for (int j = 0; j < 4; ++j) {
                const int r = (lane >> 4) * 4 + j;
                const int c = nf * 16 + (lane & 15);
                tb[r * 80 + c] = acc[mf][nf][j] + bv[nf];
            }
        __syncthreads();
#pragma unroll
        for (int jj = 0; jj < 4; ++jj) {
            const int rr = jj * 4 + (lane >> 4);
            const int cc = (lane & 15) * 4;
            f32x4 v = *(const f32x4*)&tb[rr * 80 + cc];
            *(f32x4*)&Out[(size_t)(mbase + mf * 16 + rr) * DN + nbase + cc] = v;
        }
        __syncthreads();
    }
}

extern "C" void kernel_launch(void* const* d_in, const int* in_sizes, int n_in,
                              void* d_out, int out_size, void* d_ws, size_t ws_size,
                              hipStream_t stream) {
    const float* x  = (const float*)d_in[0];
    const float* W  = (const float*)d_in[1];
    const float* b  = (const float*)d_in[2];
    const float* Vr = (const float*)d_in[3];
    const float* C  = (const float*)d_in[4];
    float* out = (float*)d_out;

    const int M = in_sizes[0] / DK;            // 65536
    bf16_t* WeffSw = (bf16_t*)d_ws;            // 2 MB pre-swizzled W_eff

    weff_kernel<<<DN, 128, 0, stream>>>(W, Vr, C, WeffSw);

    const int mtiles = M / BM;                 // 512
    const int nwg = mtiles * (DN / BN);        // 2048
    corrlin_gemm_kernel<<<nwg, 512, 0, stream>>>(x, WeffSw, b, out);
}